// Round 5
// baseline (137.126 us; speedup 1.0000x reference)
//
#include <hip/hip_runtime.h>
#include <hip/hip_bf16.h>

#define N_    16
#define V_    5023
#define F_    9976
#define HW_   (512*512)
#define NV_   (N_*V_)      // 80368
#define NF_   (N_*F_)      // 159616
#define NPIX_ (N_*HW_)     // 4194304
#define MMB_  64           // minmax partial blocks

// native clang vectors — required by __builtin_nontemporal_* (HIP float4 is a struct)
typedef float f32x4 __attribute__((ext_vector_type(4)));
typedef int   i32x4 __attribute__((ext_vector_type(4)));

// ---- ordered-float <-> uint encoding (monotone over all finite floats) ----
__device__ __forceinline__ unsigned int encf(float f) {
    unsigned int b = __float_as_uint(f);
    return (b & 0x80000000u) ? ~b : (b | 0x80000000u);
}
__device__ __forceinline__ float decf(unsigned int e) {
    unsigned int b = (e & 0x80000000u) ? (e & 0x7FFFFFFFu) : ~e;
    return __uint_as_float(b);
}

// Kernel 1: per-block min/max partials over tv[:,:,2].
// partial[b] = {enc(max), enc(min)} — unconditionally rewritten every call.
__global__ __launch_bounds__(256) void minmax_kernel(
        const float* __restrict__ tv, uint2* __restrict__ partial) {
    float vmin = 1e30f, vmax = -1e30f;
    for (int i = blockIdx.x * 256 + threadIdx.x; i < NV_; i += MMB_ * 256) {
        float z = tv[3*i + 2];
        vmin = fminf(vmin, z);
        vmax = fmaxf(vmax, z);
    }
#pragma unroll
    for (int off = 32; off > 0; off >>= 1) {
        vmin = fminf(vmin, __shfl_down(vmin, off));
        vmax = fmaxf(vmax, __shfl_down(vmax, off));
    }
    __shared__ float smin[4], smax[4];
    const int lane = threadIdx.x & 63, w = threadIdx.x >> 6;
    if (lane == 0) { smin[w] = vmin; smax[w] = vmax; }
    __syncthreads();
    if (threadIdx.x == 0) {
        float m = fminf(fminf(smin[0], smin[1]), fminf(smin[2], smin[3]));
        float M = fmaxf(fmaxf(smax[0], smax[1]), fmaxf(smax[2], smax[3]));
        partial[blockIdx.x] = make_uint2(encf(M), encf(m));
    }
}

// Kernel 2: each block redundantly reduces the 64 partials (wave 0), then
// builds face_attr[n*F+f] = {zval(v0), zval(v1), zval(v2), 0}.
// zval(v) = (zmax - tv[n,v,2]) / (zmax - zmin). Table = 2.55 MB, L2-resident.
__global__ __launch_bounds__(256) void table_kernel(
        const float* __restrict__ tv, const int* __restrict__ faces,
        const uint2* __restrict__ partial, f32x4* __restrict__ table) {
    __shared__ float s_zmax, s_inv;
    if (threadIdx.x < 64) {
        uint2 p = partial[threadIdx.x];            // MMB_ == 64 == wave width
        unsigned int eM = p.x, em = p.y;
#pragma unroll
        for (int off = 32; off > 0; off >>= 1) {
            eM = max(eM, (unsigned int)__shfl_down((int)eM, off));
            em = min(em, (unsigned int)__shfl_down((int)em, off));
        }
        if (threadIdx.x == 0) {
            float zmax = decf(eM);
            s_zmax = zmax;
            s_inv  = 1.0f / (zmax - decf(em));
        }
    }
    __syncthreads();
    const int f = blockIdx.x * 256 + threadIdx.x;
    if (f >= F_) return;
    const int n = blockIdx.y;
    const float zmax = s_zmax, inv = s_inv;
    const int v0 = faces[3*f], v1 = faces[3*f + 1], v2 = faces[3*f + 2];
    const float* base = tv + n * (V_ * 3);
    f32x4 o;
    o.x = (zmax - base[3*v0 + 2]) * inv;
    o.y = (zmax - base[3*v1 + 2]) * inv;
    o.z = (zmax - base[3*v2 + 2]) * inv;
    o.w = 0.0f;
    table[n * F_ + f] = o;
}

// Kernel 3: render, 4 pixels/thread. Streams (p2f, bary, out) use nontemporal
// loads/stores so the 2.55 MB table stays L2-resident. Gathers are branchless
// (clamped index + select) so all 4 dwordx4 gathers issue back-to-back.
__global__ __launch_bounds__(256) void render_kernel(
        const int*    __restrict__ p2f,    // (NPIX) int32
        const float*  __restrict__ bary,   // (NPIX,3) f32
        const f32x4*  __restrict__ table,  // (N*F) f32x4
        float*        __restrict__ out) {  // (NPIX) f32
    const int t = blockIdx.x * 256 + threadIdx.x;   // pixels 4t .. 4t+3
    const i32x4 pp  = __builtin_nontemporal_load((const i32x4*)p2f + t);
    const f32x4 ba0 = __builtin_nontemporal_load((const f32x4*)bary + 3*t + 0);
    const f32x4 ba1 = __builtin_nontemporal_load((const f32x4*)bary + 3*t + 1);
    const f32x4 ba2 = __builtin_nontemporal_load((const f32x4*)bary + 3*t + 2);

    const f32x4 a0 = table[max(pp.x, 0)];
    const f32x4 a1 = table[max(pp.y, 0)];
    const f32x4 a2 = table[max(pp.z, 0)];
    const f32x4 a3 = table[max(pp.w, 0)];

    f32x4 o;
    o.x = (pp.x >= 0) ? (ba0.x * a0.x + ba0.y * a0.y + ba0.z * a0.z) : 0.0f;
    o.y = (pp.y >= 0) ? (ba0.w * a1.x + ba1.x * a1.y + ba1.y * a1.z) : 0.0f;
    o.z = (pp.z >= 0) ? (ba1.z * a2.x + ba1.w * a2.y + ba2.x * a2.z) : 0.0f;
    o.w = (pp.w >= 0) ? (ba2.y * a3.x + ba2.z * a3.y + ba2.w * a3.z) : 0.0f;
    __builtin_nontemporal_store(o, (f32x4*)out + t);
}

extern "C" void kernel_launch(void* const* d_in, const int* in_sizes, int n_in,
                              void* d_out, int out_size, void* d_ws, size_t ws_size,
                              hipStream_t stream) {
    const float* tv    = (const float*)d_in[0];  // f32 (N,V,3)
    const float* bary  = (const float*)d_in[1];  // f32 (N,H,W,1,3)
    const int*   faces = (const int*)d_in[2];    // int32 (F,3)
    const int*   p2f   = (const int*)d_in[3];    // int32 (N,H,W,1)
    float* outp = (float*)d_out;

    uint2* partial = (uint2*)d_ws;                     // 64 * 8 B
    f32x4* table   = (f32x4*)((char*)d_ws + 1024);     // 2.55 MB, 16B-aligned

    minmax_kernel<<<MMB_, 256, 0, stream>>>(tv, partial);
    dim3 tgrid((F_ + 255) / 256, N_);
    table_kernel<<<tgrid, 256, 0, stream>>>(tv, faces, partial, table);
    render_kernel<<<NPIX_ / 4 / 256, 256, 0, stream>>>(p2f, bary, table, outp);
}